// Round 10
// baseline (364.292 us; speedup 1.0000x reference)
//
#include <hip/hip_runtime.h>

typedef __attribute__((ext_vector_type(8))) __bf16 bf16x8;
typedef __attribute__((ext_vector_type(4))) __bf16 bf16x4;
typedef __attribute__((ext_vector_type(4))) float f32x4;

#define GLD16(gp, lp) __builtin_amdgcn_global_load_lds( \
    (const __attribute__((address_space(1))) void*)(gp), \
    (__attribute__((address_space(3))) void*)(lp), 16, 0, 0)

__device__ __forceinline__ void cvt8(const float* __restrict__ in, __bf16* __restrict__ out) {
  float4 a = *(const float4*)in;
  float4 b = *(const float4*)(in + 4);
  bf16x8 o;
  o[0] = (__bf16)a.x; o[1] = (__bf16)a.y; o[2] = (__bf16)a.z; o[3] = (__bf16)a.w;
  o[4] = (__bf16)b.x; o[5] = (__bf16)b.y; o[6] = (__bf16)b.z; o[7] = (__bf16)b.w;
  *(bf16x8*)out = o;
}

// ---------------- hs f32 -> bf16 ----------------
__global__ __launch_bounds__(256) void cvt_f32_bf16(const float* __restrict__ in,
                                                    __bf16* __restrict__ out, long n) {
  long stride = (long)gridDim.x * 256 * 8;
  for (long i = ((long)blockIdx.x * 256 + threadIdx.x) * 8; i < n; i += stride)
    cvt8(in + i, out + i);
}

// ---------------- weights cvt + bias concat + sums zero (one launch) ----------------
// grid 512 x 256: id0 in [0,131072); covers 1M elems per matrix at 8/thread.
__global__ __launch_bounds__(256) void cvt_weights(
    const float* __restrict__ Wq, const float* __restrict__ Wk,
    const float* __restrict__ Wv, const float* __restrict__ bq,
    const float* __restrict__ bk, __bf16* __restrict__ Wqk,
    __bf16* __restrict__ Wvb, float* __restrict__ bcat,
    float* __restrict__ sums) {
  const long M = 1024 * 1024;
  long id0 = (long)blockIdx.x * 256 + threadIdx.x;
  long i = id0 * 8;
  if (i < M) {
    cvt8(Wq + i, Wqk + i);
    cvt8(Wk + i, Wqk + M + i);
    cvt8(Wv + i, Wvb + i);
  }
  if (id0 < 1024) { bcat[id0] = bq[id0]; bcat[1024 + id0] = bk[id0]; }
  if (id0 < 16384) sums[id0] = 0.f;
}

// ---------------- generic C = A @ B^T (+bias) GEMM ----------------
// A [M][K], BT [N][K] bf16 row-major. BM=BN=128, BK=32, 4 waves.
// EPI 0: C bf16 row-major [M][N] + bias
// EPI 1: C bf16 transposed per batch: C[batch][n][tok], batch=row/tokPerBatch (+bias)
template <int EPI>
__global__ __launch_bounds__(256) void gemm_bt(
    const __bf16* __restrict__ A, const __bf16* __restrict__ BT,
    void* __restrict__ Cv, const float* __restrict__ bias,
    int M, int N, int K, int tokPerBatch) {
  __shared__ __bf16 As[128 * 32];
  __shared__ __bf16 Bs[128 * 32];

  const int t = threadIdx.x;
  const int w = t >> 6, l = t & 63;
  const int wr = w >> 1, wc = w & 1;
  const int lr = l & 15, lg = l >> 4;

  const int m0 = blockIdx.y * 128, n0 = blockIdx.x * 128;
  const __bf16* Ab = A + (long)m0 * K;
  const __bf16* Bb = BT + (long)n0 * K;

  const int srow = t >> 2, scol = (t & 3) * 8;
  const __bf16* ag0 = Ab + (long)srow * K + scol;
  const __bf16* bg0 = Bb + (long)srow * K + scol;
  char* lA = (char*)As + w * 1024;  // wave-uniform LDS base; HW adds lane*16
  char* lB = (char*)Bs + w * 1024;

  f32x4 acc[4][4];
#pragma unroll
  for (int m = 0; m < 4; ++m)
#pragma unroll
    for (int n = 0; n < 4; ++n) acc[m][n] = (f32x4){0.f, 0.f, 0.f, 0.f};

  for (int k0 = 0; k0 < K; k0 += 32) {
    __syncthreads();
    GLD16(ag0 + k0, lA);
    GLD16(ag0 + (long)64 * K + k0, lA + 4096);
    GLD16(bg0 + k0, lB);
    GLD16(bg0 + (long)64 * K + k0, lB + 4096);
    __syncthreads();

    bf16x8 af[4], bf[4];
#pragma unroll
    for (int m = 0; m < 4; ++m)
      af[m] = *(const bf16x8*)&As[(wr * 64 + m * 16 + lr) * 32 + lg * 8];
#pragma unroll
    for (int n = 0; n < 4; ++n)
      bf[n] = *(const bf16x8*)&Bs[(wc * 64 + n * 16 + lr) * 32 + lg * 8];
#pragma unroll
    for (int m = 0; m < 4; ++m)
#pragma unroll
      for (int n = 0; n < 4; ++n)
        acc[m][n] = __builtin_amdgcn_mfma_f32_16x16x32_bf16(af[m], bf[n], acc[m][n], 0, 0, 0);
  }

  if constexpr (EPI == 0) {
    __bf16* C = (__bf16*)Cv;
#pragma unroll
    for (int m = 0; m < 4; ++m)
#pragma unroll
      for (int n = 0; n < 4; ++n) {
        int colg = n0 + wc * 64 + n * 16 + lr;
        float bv = bias ? bias[colg] : 0.f;
#pragma unroll
        for (int r = 0; r < 4; ++r) {
          int rowg = m0 + wr * 64 + m * 16 + lg * 4 + r;
          C[(long)rowg * N + colg] = (__bf16)(acc[m][n][r] + bv);
        }
      }
  } else {
    // transposed epilogue via LDS: Cs[col][row], ld = 136
    __shared__ __bf16 Cs[128 * 136];
#pragma unroll
    for (int m = 0; m < 4; ++m)
#pragma unroll
      for (int n = 0; n < 4; ++n) {
        int cl = wc * 64 + n * 16 + lr;
        float bv = bias ? bias[n0 + cl] : 0.f;
        bf16x4 tmp;
#pragma unroll
        for (int r = 0; r < 4; ++r) tmp[r] = (__bf16)(acc[m][n][r] + bv);
        int rl0 = wr * 64 + m * 16 + lg * 4;
        *(bf16x4*)&Cs[cl * 136 + rl0] = tmp;
      }
    __syncthreads();
    int c = t >> 1, half = t & 1;
    long batch = m0 / tokPerBatch;
    int tok0 = (m0 % tokPerBatch) + half * 64;
    __bf16* C = (__bf16*)Cv + batch * (long)N * tokPerBatch + (long)(n0 + c) * tokPerBatch + tok0;
#pragma unroll
    for (int j = 0; j < 8; ++j)
      *(bf16x8*)(C + j * 8) = *(const bf16x8*)&Cs[c * 136 + half * 64 + j * 8];
  }
}

// ---------------- QK^T + exp + row-sum GEMM ----------------
// QK buffer [8192][2048]: Q in cols 0-1023, K in cols 1024-2047.
// grid (16, 16, 8 = batch*2+half), 256 threads.
__global__ __launch_bounds__(256) void qk_gemm(
    const __bf16* __restrict__ QK,
    __bf16* __restrict__ E1, __bf16* __restrict__ E2,
    float* __restrict__ sums) {
  __shared__ __bf16 As[128 * 32];
  __shared__ __bf16 Bs[128 * 32];
  __shared__ __bf16 Cs[128 * 136];  // [row][col] tile of E, ld=136

  const int t = threadIdx.x;
  const int w = t >> 6, l = t & 63;
  const int wr = w >> 1, wc = w & 1;
  const int lr = l & 15, lg = l >> 4;
  const int z = blockIdx.z, b = z >> 1, h = z & 1;
  const int m0 = blockIdx.y * 128, n0 = blockIdx.x * 128;

  const __bf16* Ab = QK + ((long)b * 2048 + m0) * 2048 + h * 512;
  const __bf16* Bb = QK + ((long)b * 2048 + n0) * 2048 + 1024 + h * 512;

  const int srow = t >> 2, scol = (t & 3) * 8;
  const __bf16* ag0 = Ab + (long)srow * 2048 + scol;
  const __bf16* bg0 = Bb + (long)srow * 2048 + scol;
  char* lA = (char*)As + w * 1024;
  char* lB = (char*)Bs + w * 1024;

  f32x4 acc[4][4];
#pragma unroll
  for (int m = 0; m < 4; ++m)
#pragma unroll
    for (int n = 0; n < 4; ++n) acc[m][n] = (f32x4){0.f, 0.f, 0.f, 0.f};

  for (int k0 = 0; k0 < 512; k0 += 32) {
    __syncthreads();
    GLD16(ag0 + k0, lA);
    GLD16(ag0 + (long)64 * 2048 + k0, lA + 4096);
    GLD16(bg0 + k0, lB);
    GLD16(bg0 + (long)64 * 2048 + k0, lB + 4096);
    __syncthreads();

    bf16x8 af[4], bf[4];
#pragma unroll
    for (int m = 0; m < 4; ++m)
      af[m] = *(const bf16x8*)&As[(wr * 64 + m * 16 + lr) * 32 + lg * 8];
#pragma unroll
    for (int n = 0; n < 4; ++n)
      bf[n] = *(const bf16x8*)&Bs[(wc * 64 + n * 16 + lr) * 32 + lg * 8];
#pragma unroll
    for (int m = 0; m < 4; ++m)
#pragma unroll
      for (int n = 0; n < 4; ++n)
        acc[m][n] = __builtin_amdgcn_mfma_f32_16x16x32_bf16(af[m], bf[n], acc[m][n], 0, 0, 0);
  }

  // epilogue: exp, stage to LDS, partial row sums
  const float s = 0.03125f;  // 1/sqrt(1024)
  float ps[4][4];
#pragma unroll
  for (int m = 0; m < 4; ++m)
#pragma unroll
    for (int r = 0; r < 4; ++r) ps[m][r] = 0.f;

#pragma unroll
  for (int m = 0; m < 4; ++m)
#pragma unroll
    for (int n = 0; n < 4; ++n) {
      int cl = wc * 64 + n * 16 + lr;
      int rl0 = wr * 64 + m * 16 + lg * 4;
#pragma unroll
      for (int r = 0; r < 4; ++r) {
        float e = __expf(acc[m][n][r] * s);
        ps[m][r] += e;
        Cs[(rl0 + r) * 136 + cl] = (__bf16)e;
      }
    }

#pragma unroll
  for (int m = 0; m < 4; ++m)
#pragma unroll
    for (int r = 0; r < 4; ++r) {
#pragma unroll
      for (int msk = 1; msk < 16; msk <<= 1)
        ps[m][r] += __shfl_xor(ps[m][r], msk, 64);
    }
  if (lr == 0) {
    float* sb = sums + (long)h * 8192 + (long)b * 2048 + m0 + wr * 64;
#pragma unroll
    for (int m = 0; m < 4; ++m)
#pragma unroll
      for (int r = 0; r < 4; ++r)
        atomicAdd(&sb[m * 16 + lg * 4 + r], ps[m][r]);
  }

  __syncthreads();
  __bf16* EX = h ? E2 : E1;
  int row = t >> 1, half = t & 1;
  __bf16* C = EX + ((long)b * 2048 + m0 + row) * 2048 + n0 + half * 64;
  const __bf16* src = &Cs[row * 136 + half * 64];
#pragma unroll
  for (int j = 0; j < 8; ++j)
    *(bf16x8*)(C + j * 8) = *(const bf16x8*)(src + j * 8);
}

// ---------------- PV GEMM with fused combine ----------------
// Out[z,q,:] = (1/s1[q]) * sum_k (E1[q,k] - alpha[q]*E2[q,k]) * VT[:,k]
// alpha[q] = sc * s1[q]/s2[q].  A reg-staged with on-the-fly combine; B via GLD16.
// grid (8, 16, 4), 256 threads.
__global__ __launch_bounds__(256) void pv_gemm(
    const __bf16* __restrict__ E1, const __bf16* __restrict__ E2,
    const __bf16* __restrict__ VT, float* __restrict__ Out,
    const float* __restrict__ sums, const float* __restrict__ scalar) {
  __shared__ __bf16 As[128 * 32];
  __shared__ __bf16 Bs[128 * 32];

  const int t = threadIdx.x;
  const int w = t >> 6, l = t & 63;
  const int wr = w >> 1, wc = w & 1;
  const int lr = l & 15, lg = l >> 4;
  const int z = blockIdx.z;
  const int m0 = blockIdx.y * 128, n0 = blockIdx.x * 128;

  const int srow = t >> 2, scol = (t & 3) * 8;
  const long eOff = (long)z * 2048 * 2048 + (long)m0 * 2048 + (long)srow * 2048 + scol;
  const __bf16* e1r = E1 + eOff;
  const __bf16* e2r = E2 + eOff;
  const long rstep = (long)64 * 2048;

  const float scv = scalar[0];
  const float* s1 = sums + (long)z * 2048 + m0;
  const float* s2 = s1 + 8192;
  const float a0 = scv * s1[srow] / s2[srow];
  const float a1 = scv * s1[srow + 64] / s2[srow + 64];

  const __bf16* bg0 = VT + (long)z * 1024 * 2048 + ((long)n0 + srow) * 2048 + scol;
  char* lB = (char*)Bs + w * 1024;
  __bf16* aw0 = &As[srow * 32 + scol];
  __bf16* aw1 = &As[(srow + 64) * 32 + scol];

  f32x4 acc[4][4];
#pragma unroll
  for (int m = 0; m < 4; ++m)
#pragma unroll
    for (int n = 0; n < 4; ++n) acc[m][n] = (f32x4){0.f, 0.f, 0.f, 0.f};

  for (int k0 = 0; k0 < 2048; k0 += 32) {
    bf16x8 x10 = *(const bf16x8*)(e1r + k0);
    bf16x8 x20 = *(const bf16x8*)(e2r + k0);
    bf16x8 x11 = *(const bf16x8*)(e1r + rstep + k0);
    bf16x8 x21 = *(const bf16x8*)(e2r + rstep + k0);
    bf16x8 p0, p1;
#pragma unroll
    for (int i = 0; i < 8; ++i) {
      p0[i] = (__bf16)fmaf(-a0, (float)x20[i], (float)x10[i]);
      p1[i] = (__bf16)fmaf(-a1, (float)x21[i], (float)x11[i]);
    }
    __syncthreads();
    GLD16(bg0 + k0, lB);
    GLD16(bg0 + (long)64 * 2048 + k0, lB + 4096);  // rows 64..127 of B tile
    *(bf16x8*)aw0 = p0;
    *(bf16x8*)aw1 = p1;
    __syncthreads();

    bf16x8 af[4], bf[4];
#pragma unroll
    for (int m = 0; m < 4; ++m)
      af[m] = *(const bf16x8*)&As[(wr * 64 + m * 16 + lr) * 32 + lg * 8];
#pragma unroll
    for (int n = 0; n < 4; ++n)
      bf[n] = *(const bf16x8*)&Bs[(wc * 64 + n * 16 + lr) * 32 + lg * 8];
#pragma unroll
    for (int m = 0; m < 4; ++m)
#pragma unroll
      for (int n = 0; n < 4; ++n)
        acc[m][n] = __builtin_amdgcn_mfma_f32_16x16x32_bf16(af[m], bf[n], acc[m][n], 0, 0, 0);
  }

  float rs[4][4];
#pragma unroll
  for (int m = 0; m < 4; ++m)
#pragma unroll
    for (int r = 0; r < 4; ++r)
      rs[m][r] = 1.0f / s1[wr * 64 + m * 16 + lg * 4 + r];
#pragma unroll
  for (int m = 0; m < 4; ++m)
#pragma unroll
    for (int n = 0; n < 4; ++n) {
      int colg = n0 + wc * 64 + n * 16 + lr;
#pragma unroll
      for (int r = 0; r < 4; ++r) {
        int rowl = wr * 64 + m * 16 + lg * 4 + r;
        Out[((long)z * 2048 + m0 + rowl) * 1024 + colg] = acc[m][n][r] * rs[m][r];
      }
    }
}

__global__ void diag_kernel(float* out, float v) { out[0] = v; }

// ---------------- host ----------------
extern "C" void kernel_launch(void* const* d_in, const int* in_sizes, int n_in,
                              void* d_out, int out_size, void* d_ws, size_t ws_size,
                              hipStream_t stream) {
  const float* hs = (const float*)d_in[0];
  const float* Wq = (const float*)d_in[1];
  const float* bq = (const float*)d_in[2];
  const float* Wk = (const float*)d_in[3];
  const float* bk = (const float*)d_in[4];
  const float* Wv = (const float*)d_in[5];
  const float* bv = (const float*)d_in[6];
  const float* sc = (const float*)d_in[7];

  const long SZ_HS = (long)4 * 2048 * 1024;        // 8.39M elems
  const long SZ_QK = (long)8192 * 2048;            // 16.8M elems
  const long SZ_E = (long)4 * 2048 * 2048;         // 16.8M elems
  const size_t NEED = (size_t)SZ_QK * 2 + (size_t)SZ_HS * 2 /*VT*/ +
                      (size_t)SZ_E * 2 * 2 /*E1,E2*/ +
                      (size_t)(2048 + 1024) * 1024 * 2 /*Wqk,Wvb*/ +
                      2048 * 4 + 16384 * 4;
  if (ws_size < NEED) {
    diag_kernel<<<dim3(1), dim3(1), 0, stream>>>((float*)d_out, (float)ws_size);
    return;
  }

  char* ws = (char*)d_ws;
  __bf16* QKb = (__bf16*)ws;  ws += SZ_QK * 2;            // [8192][2048]
  __bf16* VT = (__bf16*)ws;   ws += SZ_HS * 2;            // [4][1024][2048]
  __bf16* E1 = (__bf16*)ws;   ws += SZ_E * 2;             // also hosts hsb (dead before E1 written)
  __bf16* E2 = (__bf16*)ws;   ws += SZ_E * 2;
  __bf16* Wqk = (__bf16*)ws;  ws += (long)2048 * 1024 * 2;
  __bf16* Wvb = (__bf16*)ws;  ws += (long)1024 * 1024 * 2;
  float* bcat = (float*)ws;   ws += 2048 * 4;
  float* sums = (float*)ws;                                 // [2][8192]
  __bf16* hsb = E1;  // aliased: consumed by projections before qk writes E1

  dim3 blk(256);
  cvt_f32_bf16<<<dim3(2048), blk, 0, stream>>>(hs, hsb, SZ_HS);
  cvt_weights<<<dim3(512), blk, 0, stream>>>(Wq, Wk, Wv, bq, bk, Wqk, Wvb, bcat, sums);

  gemm_bt<0><<<dim3(16, 64, 1), blk, 0, stream>>>(hsb, Wqk, QKb, bcat, 8192, 2048, 1024, 2048);
  gemm_bt<1><<<dim3(8, 64, 1), blk, 0, stream>>>(hsb, Wvb, VT, bv, 8192, 1024, 1024, 2048);

  qk_gemm<<<dim3(16, 16, 8), blk, 0, stream>>>(QKb, E1, E2, sums);
  pv_gemm<<<dim3(8, 16, 4), blk, 0, stream>>>(E1, E2, VT, (float*)d_out, sums, sc);
}

// Round 12
// 337.136 us; speedup vs baseline: 1.0805x; 1.0805x over previous
//
#include <hip/hip_runtime.h>

typedef __attribute__((ext_vector_type(8))) __bf16 bf16x8;
typedef __attribute__((ext_vector_type(4))) __bf16 bf16x4;
typedef __attribute__((ext_vector_type(4))) float f32x4;

#define GLD16(gp, lp) __builtin_amdgcn_global_load_lds( \
    (const __attribute__((address_space(1))) void*)(gp), \
    (__attribute__((address_space(3))) void*)(lp), 16, 0, 0)

// XCD-aware swizzle: hw-linear block id -> (n-tile, panel). All nx n-blocks of
// a panel get the same lin&7 -> same XCD -> shared A-rows stay in that L2.
// Bijective when total blocks % 8 == 0 and npanels % 8 == 0.
__device__ __forceinline__ int2 xcd_swz(int nx, int npanels) {
  int lin = blockIdx.x + gridDim.x * (blockIdx.y + gridDim.y * blockIdx.z);
  int ppx = npanels >> 3;  // panels per XCD
  int c = lin & 7, j = lin >> 3;
  int q = j / nx;
  return make_int2(j - q * nx, c * ppx + q);
}

__device__ __forceinline__ void cvt8(const float* __restrict__ in, __bf16* __restrict__ out) {
  float4 a = *(const float4*)in;
  float4 b = *(const float4*)(in + 4);
  bf16x8 o;
  o[0] = (__bf16)a.x; o[1] = (__bf16)a.y; o[2] = (__bf16)a.z; o[3] = (__bf16)a.w;
  o[4] = (__bf16)b.x; o[5] = (__bf16)b.y; o[6] = (__bf16)b.z; o[7] = (__bf16)b.w;
  *(bf16x8*)out = o;
}

// ---------------- hs f32 -> bf16 ----------------
__global__ __launch_bounds__(256) void cvt_f32_bf16(const float* __restrict__ in,
                                                    __bf16* __restrict__ out, long n) {
  long stride = (long)gridDim.x * 256 * 8;
  for (long i = ((long)blockIdx.x * 256 + threadIdx.x) * 8; i < n; i += stride)
    cvt8(in + i, out + i);
}

// ---------------- weights cvt + bias concat + sums zero (one launch) ----------------
__global__ __launch_bounds__(256) void cvt_weights(
    const float* __restrict__ Wq, const float* __restrict__ Wk,
    const float* __restrict__ Wv, const float* __restrict__ bq,
    const float* __restrict__ bk, __bf16* __restrict__ Wqk,
    __bf16* __restrict__ Wvb, float* __restrict__ bcat,
    float* __restrict__ sums) {
  const long M = 1024 * 1024;
  long id0 = (long)blockIdx.x * 256 + threadIdx.x;
  long i = id0 * 8;
  if (i < M) {
    cvt8(Wq + i, Wqk + i);
    cvt8(Wk + i, Wqk + M + i);
    cvt8(Wv + i, Wvb + i);
  }
  if (id0 < 1024) { bcat[id0] = bq[id0]; bcat[1024 + id0] = bk[id0]; }
  if (id0 < 16384) sums[id0] = 0.f;
}

// ---------------- generic C = A @ B^T (+bias) GEMM ----------------
// A [M][K], BT [N][K] bf16 row-major. BM=BN=128, BK=32, 4 waves. grid (nx, ny, 1).
// EPI 0: C bf16 row-major [M][N] + bias
// EPI 1: C bf16 transposed per batch: C[batch][n][tok], batch=row/tokPerBatch (+bias)
template <int EPI>
__global__ __launch_bounds__(256) void gemm_bt(
    const __bf16* __restrict__ A, const __bf16* __restrict__ BT,
    void* __restrict__ Cv, const float* __restrict__ bias,
    int M, int N, int K, int tokPerBatch) {
  __shared__ __bf16 As[128 * 32];
  __shared__ __bf16 Bs[128 * 32];

  const int t = threadIdx.x;
  const int w = t >> 6, l = t & 63;
  const int wr = w >> 1, wc = w & 1;
  const int lr = l & 15, lg = l >> 4;

  int2 swz = xcd_swz(gridDim.x, gridDim.y);
  const int m0 = swz.y * 128, n0 = swz.x * 128;
  const __bf16* Ab = A + (long)m0 * K;
  const __bf16* Bb = BT + (long)n0 * K;

  const int srow = t >> 2, scol = (t & 3) * 8;
  const __bf16* ag0 = Ab + (long)srow * K + scol;
  const __bf16* bg0 = Bb + (long)srow * K + scol;
  char* lA = (char*)As + w * 1024;  // wave-uniform LDS base; HW adds lane*16
  char* lB = (char*)Bs + w * 1024;

  f32x4 acc[4][4];
#pragma unroll
  for (int m = 0; m < 4; ++m)
#pragma unroll
    for (int n = 0; n < 4; ++n) acc[m][n] = (f32x4){0.f, 0.f, 0.f, 0.f};

  for (int k0 = 0; k0 < K; k0 += 32) {
    __syncthreads();
    GLD16(ag0 + k0, lA);
    GLD16(ag0 + (long)64 * K + k0, lA + 4096);
    GLD16(bg0 + k0, lB);
    GLD16(bg0 + (long)64 * K + k0, lB + 4096);
    __syncthreads();

    bf16x8 af[4], bf[4];
#pragma unroll
    for (int m = 0; m < 4; ++m)
      af[m] = *(const bf16x8*)&As[(wr * 64 + m * 16 + lr) * 32 + lg * 8];
#pragma unroll
    for (int n = 0; n < 4; ++n)
      bf[n] = *(const bf16x8*)&Bs[(wc * 64 + n * 16 + lr) * 32 + lg * 8];
#pragma unroll
    for (int m = 0; m < 4; ++m)
#pragma unroll
      for (int n = 0; n < 4; ++n)
        acc[m][n] = __builtin_amdgcn_mfma_f32_16x16x32_bf16(af[m], bf[n], acc[m][n], 0, 0, 0);
  }

  if constexpr (EPI == 0) {
    __bf16* C = (__bf16*)Cv;
#pragma unroll
    for (int m = 0; m < 4; ++m)
#pragma unroll
      for (int n = 0; n < 4; ++n) {
        int colg = n0 + wc * 64 + n * 16 + lr;
        float bv = bias ? bias[colg] : 0.f;
#pragma unroll
        for (int r = 0; r < 4; ++r) {
          int rowg = m0 + wr * 64 + m * 16 + lg * 4 + r;
          C[(long)rowg * N + colg] = (__bf16)(acc[m][n][r] + bv);
        }
      }
  } else {
    // transposed epilogue via LDS: Cs[col][row], ld = 136
    __shared__ __bf16 Cs[128 * 136];
#pragma unroll
    for (int m = 0; m < 4; ++m)
#pragma unroll
      for (int n = 0; n < 4; ++n) {
        int cl = wc * 64 + n * 16 + lr;
        float bv = bias ? bias[n0 + cl] : 0.f;
        bf16x4 tmp;
#pragma unroll
        for (int r = 0; r < 4; ++r) tmp[r] = (__bf16)(acc[m][n][r] + bv);
        int rl0 = wr * 64 + m * 16 + lg * 4;
        *(bf16x4*)&Cs[cl * 136 + rl0] = tmp;
      }
    __syncthreads();
    int c = t >> 1, half = t & 1;
    long batch = m0 / tokPerBatch;
    int tok0 = (m0 % tokPerBatch) + half * 64;
    __bf16* C = (__bf16*)Cv + batch * (long)N * tokPerBatch + (long)(n0 + c) * tokPerBatch + tok0;
#pragma unroll
    for (int j = 0; j < 8; ++j)
      *(bf16x8*)(C + j * 8) = *(const bf16x8*)&Cs[c * 136 + half * 64 + j * 8];
  }
}

// ---------------- QK^T + exp + row-sum GEMM ----------------
// QK buffer [8192][2048]: Q in cols 0-1023, K in cols 1024-2047.
// grid (16, 16, 8), 256 threads. Swizzled: XCD c owns z==c entirely
// (Q-half + K-half = 4 MB -> L2-resident).
__global__ __launch_bounds__(256) void qk_gemm(
    const __bf16* __restrict__ QK,
    __bf16* __restrict__ E1, __bf16* __restrict__ E2,
    float* __restrict__ sums) {
  __shared__ __bf16 As[128 * 32];
  __shared__ __bf16 Bs[128 * 32];
  __shared__ __bf16 Cs[128 * 136];  // [row][col] tile of E, ld=136

  const int t = threadIdx.x;
  const int w = t >> 6, l = t & 63;
  const int wr = w >> 1, wc = w & 1;
  const int lr = l & 15, lg = l >> 4;

  int2 swz = xcd_swz(16, 128);          // panel = z*16 + m
  const int z = swz.y >> 4, b = z >> 1, h = z & 1;
  const int m0 = (swz.y & 15) * 128, n0 = swz.x * 128;

  const __bf16* Ab = QK + ((long)b * 2048 + m0) * 2048 + h * 512;
  const __bf16* Bb = QK + ((long)b * 2048 + n0) * 2048 + 1024 + h * 512;

  const int srow = t >> 2, scol = (t & 3) * 8;
  const __bf16* ag0 = Ab + (long)srow * 2048 + scol;
  const __bf16* bg0 = Bb + (long)srow * 2048 + scol;
  char* lA = (char*)As + w * 1024;
  char* lB = (char*)Bs + w * 1024;

  f32x4 acc[4][4];
#pragma unroll
  for (int m = 0; m < 4; ++m)
#pragma unroll
    for (int n = 0; n < 4; ++n) acc[m][n] = (f32x4){0.f, 0.f, 0.f, 0.f};

  for (int k0 = 0; k0 < 512; k0 += 32) {
    __syncthreads();
    GLD16(ag0 + k0, lA);
    GLD16(ag0 + (long)64 * 2048 + k0, lA + 4096);
    GLD16(bg0 + k0, lB);
    GLD16(bg0 + (long)64 * 2048 + k0, lB + 4096);
    __syncthreads();

    bf16x8 af[4], bf[4];
#pragma unroll
    for (int m = 0; m < 4; ++m)
      af[m] = *(const bf16x8*)&As[(wr * 64 + m * 16 + lr) * 32 + lg * 8];
#pragma unroll
    for (int n = 0; n < 4; ++n)
      bf[n] = *(const bf16x8*)&Bs[(wc * 64 + n * 16 + lr) * 32 + lg * 8];
#pragma unroll
    for (int m = 0; m < 4; ++m)
#pragma unroll
      for (int n = 0; n < 4; ++n)
        acc[m][n] = __builtin_amdgcn_mfma_f32_16x16x32_bf16(af[m], bf[n], acc[m][n], 0, 0, 0);
  }

  // epilogue: exp, stage to LDS, partial row sums
  const float s = 0.03125f;  // 1/sqrt(1024)
  float ps[4][4];
#pragma unroll
  for (int m = 0; m < 4; ++m)
#pragma unroll
    for (int r = 0; r < 4; ++r) ps[m][r] = 0.f;

#pragma unroll
  for (int m = 0; m < 4; ++m)
#pragma unroll
    for (int n = 0; n < 4; ++n) {
      int cl = wc * 64 + n * 16 + lr;
      int rl0 = wr * 64 + m * 16 + lg * 4;
#pragma unroll
      for (int r = 0; r < 4; ++r) {
        float e = __expf(acc[m][n][r] * s);
        ps[m][r] += e;
        Cs[(rl0 + r) * 136 + cl] = (__bf16)e;
      }
    }

#pragma unroll
  for (int m = 0; m < 4; ++m)
#pragma unroll
    for (int r = 0; r < 4; ++r) {
#pragma unroll
      for (int msk = 1; msk < 16; msk <<= 1)
        ps[m][r] += __shfl_xor(ps[m][r], msk, 64);
    }
  if (lr == 0) {
    float* sb = sums + (long)h * 8192 + (long)b * 2048 + m0 + wr * 64;
#pragma unroll
    for (int m = 0; m < 4; ++m)
#pragma unroll
      for (int r = 0; r < 4; ++r)
        atomicAdd(&sb[m * 16 + lg * 4 + r], ps[m][r]);
  }

  __syncthreads();
  __bf16* EX = h ? E2 : E1;
  int row = t >> 1, half = t & 1;
  __bf16* C = EX + ((long)b * 2048 + m0 + row) * 2048 + n0 + half * 64;
  const __bf16* src = &Cs[row * 136 + half * 64];
#pragma unroll
  for (int j = 0; j < 8; ++j)
    *(bf16x8*)(C + j * 8) = *(const bf16x8*)(src + j * 8);
}

// ---------------- PV GEMM with fused combine ----------------
// Out[z,q,:] = (1/s1[q]) * sum_k (E1[q,k] - alpha[q]*E2[q,k]) * VT[:,k]
// grid (8, 16, 4), 256 threads. Swizzled: all 8 n-blocks of an E-row panel
// share one XCD L2.
__global__ __launch_bounds__(256) void pv_gemm(
    const __bf16* __restrict__ E1, const __bf16* __restrict__ E2,
    const __bf16* __restrict__ VT, float* __restrict__ Out,
    const float* __restrict__ sums, const float* __restrict__ scalar) {
  __shared__ __bf16 As[128 * 32];
  __shared__ __bf16 Bs[128 * 32];

  const int t = threadIdx.x;
  const int w = t >> 6, l = t & 63;
  const int wr = w >> 1, wc = w & 1;
  const int lr = l & 15, lg = l >> 4;

  int2 swz = xcd_swz(8, 64);            // panel = z*16 + m
  const int z = swz.y >> 4;
  const int m0 = (swz.y & 15) * 128, n0 = swz.x * 128;

  const int srow = t >> 2, scol = (t & 3) * 8;
  const long eOff = (long)z * 2048 * 2048 + (long)m0 * 2048 + (long)srow * 2048 + scol;
  const __bf16* e1r = E1 + eOff;
  const __bf16* e2r = E2 + eOff;
  const long rstep = (long)64 * 2048;

  const float scv = scalar[0];
  const float* s1 = sums + (long)z * 2048 + m0;
  const float* s2 = s1 + 8192;
  const float a0 = scv * s1[srow] / s2[srow];
  const float a1 = scv * s1[srow + 64] / s2[srow + 64];

  const __bf16* bg0 = VT + (long)z * 1024 * 2048 + ((long)n0 + srow) * 2048 + scol;
  char* lB = (char*)Bs + w * 1024;
  __bf16* aw0 = &As[srow * 32 + scol];
  __bf16* aw1 = &As[(srow + 64) * 32 + scol];

  f32x4 acc[4][4];
#pragma unroll
  for (int m = 0; m < 4; ++m)
#pragma unroll
    for (int n = 0; n < 4; ++n) acc[m][n] = (f32x4){0.f, 0.f, 0.f, 0.f};

  for (int k0 = 0; k0 < 2048; k0 += 32) {
    bf16x8 x10 = *(const bf16x8*)(e1r + k0);
    bf16x8 x20 = *(const bf16x8*)(e2r + k0);
    bf16x8 x11 = *(const bf16x8*)(e1r + rstep + k0);
    bf16x8 x21 = *(const bf16x8*)(e2r + rstep + k0);
    bf16x8 p0, p1;
#pragma unroll
    for (int i = 0; i < 8; ++i) {
      p0[i] = (__bf16)fmaf(-a0, (float)x20[i], (float)x10[i]);
      p1[i] = (__bf16)fmaf(-a1, (float)x21[i], (float)x11[i]);
    }
    __syncthreads();
    GLD16(bg0 + k0, lB);
    GLD16(bg0 + (long)64 * 2048 + k0, lB + 4096);  // rows 64..127 of B tile
    *(bf16x8*)aw0 = p0;
    *(bf16x8*)aw1 = p1;
    __syncthreads();

    bf16x8 af[4], bf[4];
#pragma unroll
    for (int m = 0; m < 4; ++m)
      af[m] = *(const bf16x8*)&As[(wr * 64 + m * 16 + lr) * 32 + lg * 8];
#pragma unroll
    for (int n = 0; n < 4; ++n)
      bf[n] = *(const bf16x8*)&Bs[(wc * 64 + n * 16 + lr) * 32 + lg * 8];
#pragma unroll
    for (int m = 0; m < 4; ++m)
#pragma unroll
      for (int n = 0; n < 4; ++n)
        acc[m][n] = __builtin_amdgcn_mfma_f32_16x16x32_bf16(af[m], bf[n], acc[m][n], 0, 0, 0);
  }

  float rs[4][4];
#pragma unroll
  for (int m = 0; m < 4; ++m)
#pragma unroll
    for (int r = 0; r < 4; ++r)
      rs[m][r] = 1.0f / s1[wr * 64 + m * 16 + lg * 4 + r];
#pragma unroll
  for (int m = 0; m < 4; ++m)
#pragma unroll
    for (int n = 0; n < 4; ++n) {
      int colg = n0 + wc * 64 + n * 16 + lr;
#pragma unroll
      for (int r = 0; r < 4; ++r) {
        int rowl = wr * 64 + m * 16 + lg * 4 + r;
        Out[((long)z * 2048 + m0 + rowl) * 1024 + colg] = acc[m][n][r] * rs[m][r];
      }
    }
}

__global__ void diag_kernel(float* out, float v) { out[0] = v; }

// ---------------- host ----------------
extern "C" void kernel_launch(void* const* d_in, const int* in_sizes, int n_in,
                              void* d_out, int out_size, void* d_ws, size_t ws_size,
                              hipStream_t stream) {
  const float* hs = (const float*)d_in[0];
  const float* Wq = (const float*)d_in[1];
  const float* bq = (const float*)d_in[2];
  const float* Wk = (const float*)d_in[3];
  const float* bk = (const float*)d_in[4];
  const float* Wv = (const float*)d_in[5];
  const float* bv = (const float*)d_in[6];
  const float* sc = (const float*)d_in[7];

  const long SZ_HS = (long)4 * 2048 * 1024;        // 8.39M elems
  const long SZ_QK = (long)8192 * 2048;            // 16.8M elems
  const long SZ_E = (long)4 * 2048 * 2048;         // 16.8M elems
  const size_t NEED = (size_t)SZ_QK * 2 + (size_t)SZ_HS * 2 /*VT*/ +
                      (size_t)SZ_E * 2 * 2 /*E1,E2*/ +
                      (size_t)(2048 + 1024) * 1024 * 2 /*Wqk,Wvb*/ +
                      2048 * 4 + 16384 * 4;
  if (ws_size < NEED) {
    diag_kernel<<<dim3(1), dim3(1), 0, stream>>>((float*)d_out, (float)ws_size);
    return;
  }

  char* ws = (char*)d_ws;
  __bf16* QKb = (__bf16*)ws;  ws += SZ_QK * 2;            // [8192][2048]
  __bf16* VT = (__bf16*)ws;   ws += SZ_HS * 2;            // [4][1024][2048]
  __bf16* E1 = (__bf16*)ws;   ws += SZ_E * 2;             // also hosts hsb (dead before E1 written)
  __bf16* E2 = (__bf16*)ws;   ws += SZ_E * 2;
  __bf16* Wqk = (__bf16*)ws;  ws += (long)2048 * 1024 * 2;
  __bf16* Wvb = (__bf16*)ws;  ws += (long)1024 * 1024 * 2;
  float* bcat = (float*)ws;   ws += 2048 * 4;
  float* sums = (float*)ws;                                 // [2][8192]
  __bf16* hsb = E1;  // aliased: consumed by projections before qk writes E1

  dim3 blk(256);
  cvt_f32_bf16<<<dim3(2048), blk, 0, stream>>>(hs, hsb, SZ_HS);
  cvt_weights<<<dim3(512), blk, 0, stream>>>(Wq, Wk, Wv, bq, bk, Wqk, Wvb, bcat, sums);

  gemm_bt<0><<<dim3(16, 64, 1), blk, 0, stream>>>(hsb, Wqk, QKb, bcat, 8192, 2048, 1024, 2048);
  gemm_bt<1><<<dim3(8, 64, 1), blk, 0, stream>>>(hsb, Wvb, VT, bv, 8192, 1024, 1024, 2048);

  qk_gemm<<<dim3(16, 16, 8), blk, 0, stream>>>(QKb, E1, E2, sums);
  pv_gemm<<<dim3(8, 16, 4), blk, 0, stream>>>(E1, E2, VT, (float*)d_out, sums, sc);
}